// Round 10
// baseline (731.421 us; speedup 1.0000x reference)
//
#include <hip/hip_runtime.h>
#include <math.h>

// ---------------- problem constants ----------------
// b=1, t=16, ch_in=10, h=w=24, t_de=16, ch_de=12, K=5, N=25
// hw=576, M = 14400; out: 27648 + loss = 27649 floats

typedef __attribute__((ext_vector_type(8))) short sh8;
typedef __attribute__((ext_vector_type(4))) float f32x4;

// ---------------- workspace layout (byte offsets) ----------------
#define OFF_PART 0UL              // 37,748,736 (max: conv2/3 16 splits x 1024x576x4)
#define OFF_X2T  37748736UL       // 21,233,664 (288 chunks x 73728)
#define OFF_WTT  37748736UL       // overlaps X2T (X2T dead when WTT written)
#define OFF_ACT  58982400UL       // 2,359,296
#define OFF_OB   61341696UL       // 2,764,800
#define OFF_LP   64106496UL       // 2,304
// total ~64.1 MB (within known-safe 85 MB)

// X2T layout: [kc][pg(36)][plane(2: hi,lo)][q(4)][px16(16)][16B]
//   chunk stride 36*2048 = 73728 B; pg block 2048 B; plane 1024 B.

// ---------------- im2col: act fp32 [C][24][24] -> X2T (frag-coalesced layout) ----------------
__global__ __launch_bounds__(256) void im2col_kernel(const float* __restrict__ act,
                                                     char* __restrict__ x2t, int nrows) {
    int row = blockIdx.x * 256 + threadIdx.x;
    if (row >= nrows) return;
    int kc = row / 576, px = row % 576;
    int y = px / 24, x = px % 24;
    int k0 = kc * 32;
    int ic = k0 / 9;
    int tap = k0 - ic * 9;
    sh8 hv[4], lv[4];
#pragma unroll
    for (int e = 0; e < 32; ++e) {
        int dy = tap / 3, dx = tap - dy * 3;
        int yy = y + dy - 1, xx = x + dx - 1;
        float v = (yy >= 0 && yy < 24 && xx >= 0 && xx < 24)
                      ? act[ic * 576 + yy * 24 + xx] : 0.0f;
        unsigned u = __builtin_bit_cast(unsigned, v);
        hv[e / 8][e % 8] = (short)(u >> 16);
        float fh = __builtin_bit_cast(float, u & 0xFFFF0000u);
        lv[e / 8][e % 8] = (short)(__builtin_bit_cast(unsigned, v - fh) >> 16);
        if (++tap == 9) { tap = 0; ++ic; }
    }
    int pg = px >> 4, l15 = px & 15;
    char* dst = x2t + (long)kc * 73728 + pg * 2048 + l15 * 16;
#pragma unroll
    for (int q = 0; q < 4; ++q) {
        *(sh8*)(dst + q * 256) = hv[q];
        *(sh8*)(dst + 1024 + q * 256) = lv[q];
    }
}

// ---------------- sum K-splits + bias + leaky -> act fp32 ----------------
__global__ void finalize_kernel(const float* __restrict__ part,
                                const float* __restrict__ bias,
                                float* __restrict__ act, int total, int nsplit) {
    int idx = blockIdx.x * 256 + threadIdx.x;
    if (idx >= total) return;
    float s = 0.0f;
    for (int k = 0; k < nsplit; k++) s += part[(long)k * total + idx];
    s += bias[idx / 576];
    act[idx] = s >= 0.0f ? s : 0.01f * s;
}

// ---------------- bf16 split (truncation hi + rounded lo via subtract) ----------------
__device__ inline void cvt_split8(const float4& a0, const float4& a1, sh8& h8, sh8& l8) {
    float av[8] = {a0.x, a0.y, a0.z, a0.w, a1.x, a1.y, a1.z, a1.w};
#pragma unroll
    for (int e = 0; e < 8; ++e) {
        unsigned u = __builtin_bit_cast(unsigned, av[e]);
        h8[e] = (short)(u >> 16);
        float fh = __builtin_bit_cast(float, u & 0xFFFF0000u);
        l8[e] = (short)(__builtin_bit_cast(unsigned, av[e] - fh) >> 16);
    }
}

// ---------------- MFMA GEMM conv (v9): ALL-REGISTER, zero LDS, zero barriers ----------------
// Block: 256 thr = 4 waves, oc-split: wave w owns 32 oc (2 ot) x 144 px (9 j).
// B: bh[9]+bl[9] persistent VGPRs; reload each fragment for chunk t+1 IMMEDIATELY after
//    its last MFMA use (WAR dep pins order) -> full-chunk (~450 cyc) lookahead. Each
//    load = one coalesced 1024-B dwordx4; 4 waves hit the same lines -> L1 absorbs 3/4.
// A: per-lane fp32 direct loads (16 lines/instr), double-buffered regs, converted to
//    bf16 hi/lo between chunks. ~200 VGPR -> 2 blocks/CU; waves never sync.
template<int SWZ>
__global__ __launch_bounds__(256, 2)
void conv_mfma9_kernel(const char* __restrict__ x2t,
                       const float* __restrict__ wgt,   // [cout][K] fp32, K = cin*9
                       float* __restrict__ part,        // [ksplit][cout][576]
                       int K, int cps, int cout) {
    const int tid = threadIdx.x;
    const int lane = tid & 63;
    const int w = tid >> 6;
    const int q = lane >> 4, ln15 = lane & 15;
    const int lane16 = lane * 16;

    int ocb, pxq, s;
    if (SWZ) {
        int g = blockIdx.x;               // 400 = 50 ocb x 4 pxq x 2 s
        int p = (g & 7) * 50 + (g >> 3);  // bijective: each XCD gets 50 consecutive slots
        ocb = p >> 3;
        int rem = p & 7;
        s = rem >> 2; pxq = rem & 3;
    } else {
        ocb = blockIdx.x; pxq = blockIdx.y; s = blockIdx.z;
    }
    const int c0 = s * cps;

    // A row pointers for this lane's two ot fragments (8 fp32 each per chunk)
    const float* arow0 = wgt + (long)(ocb * 128 + w * 32 + ln15) * K + q * 8;
    const float* arow1 = arow0 + (long)16 * K;
    const char* bbase = x2t + (long)pxq * 18432;

    f32x4 acc[2][9];
#pragma unroll
    for (int a = 0; a < 2; ++a)
#pragma unroll
        for (int j = 0; j < 9; ++j) acc[a][j] = f32x4{0.f, 0.f, 0.f, 0.f};

    // ---- prologue: B[c0] + A[c0] regs ----
    sh8 bh[9], bl[9];
    {
        const char* bc = bbase + (long)c0 * 73728;
#pragma unroll
        for (int j = 0; j < 9; ++j) {
            bh[j] = *(const sh8*)(bc + j * 2048 + lane16);
            bl[j] = *(const sh8*)(bc + j * 2048 + 1024 + lane16);
        }
    }
    sh8 ah[2], al[2];
    float4 an[4];
    {
        const float* p0 = arow0 + (long)c0 * 32;
        const float* p1 = arow1 + (long)c0 * 32;
        float4 t0 = *(const float4*)(p0), t1 = *(const float4*)(p0 + 4);
        float4 t2 = *(const float4*)(p1), t3 = *(const float4*)(p1 + 4);
        cvt_split8(t0, t1, ah[0], al[0]);
        cvt_split8(t2, t3, ah[1], al[1]);
        // issue A[c0+1]
        const int c1 = (cps > 1) ? c0 + 1 : c0;
        const float* n0 = arow0 + (long)c1 * 32;
        const float* n1 = arow1 + (long)c1 * 32;
        an[0] = *(const float4*)(n0); an[1] = *(const float4*)(n0 + 4);
        an[2] = *(const float4*)(n1); an[3] = *(const float4*)(n1 + 4);
    }

#pragma unroll 1
    for (int t = 0; t < cps; ++t) {
        const int cn = (t + 1 < cps) ? (c0 + t + 1) : (c0 + cps - 1);
        const char* bnext = bbase + (long)cn * 73728;
#pragma unroll
        for (int j = 0; j < 9; ++j) {
            sh8 bhj = bh[j];
            sh8 blj = bl[j];
            acc[0][j] = __builtin_amdgcn_mfma_f32_16x16x32_bf16(ah[0], bhj, acc[0][j], 0, 0, 0);
            acc[1][j] = __builtin_amdgcn_mfma_f32_16x16x32_bf16(ah[1], bhj, acc[1][j], 0, 0, 0);
            acc[0][j] = __builtin_amdgcn_mfma_f32_16x16x32_bf16(al[0], bhj, acc[0][j], 0, 0, 0);
            acc[1][j] = __builtin_amdgcn_mfma_f32_16x16x32_bf16(al[1], bhj, acc[1][j], 0, 0, 0);
            acc[0][j] = __builtin_amdgcn_mfma_f32_16x16x32_bf16(ah[0], blj, acc[0][j], 0, 0, 0);
            acc[1][j] = __builtin_amdgcn_mfma_f32_16x16x32_bf16(ah[1], blj, acc[1][j], 0, 0, 0);
            // reload this fragment for chunk t+1 (WAR dep keeps it after the MFMAs)
            bh[j] = *(const sh8*)(bnext + j * 2048 + lane16);
            bl[j] = *(const sh8*)(bnext + j * 2048 + 1024 + lane16);
        }
        if (t + 1 < cps) {
            // convert A[t+1] (regs arrived during this chunk), issue A[t+2]
            cvt_split8(an[0], an[1], ah[0], al[0]);
            cvt_split8(an[2], an[3], ah[1], al[1]);
            const int c2 = (t + 2 < cps) ? (c0 + t + 2) : (c0 + cps - 1);
            const float* n0 = arow0 + (long)c2 * 32;
            const float* n1 = arow1 + (long)c2 * 32;
            an[0] = *(const float4*)(n0); an[1] = *(const float4*)(n0 + 4);
            an[2] = *(const float4*)(n1); an[3] = *(const float4*)(n1 + 4);
        }
    }
    // epilogue: C row=oc (q*4+vr), col=px (ln15)
#pragma unroll
    for (int ot = 0; ot < 2; ++ot) {
        int oc0 = ocb * 128 + w * 32 + ot * 16 + q * 4;
#pragma unroll
        for (int j = 0; j < 9; ++j) {
            int px = pxq * 144 + j * 16 + ln15;
#pragma unroll
            for (int vr = 0; vr < 4; ++vr)
                part[((long)s * cout + oc0 + vr) * 576 + px] = acc[ot][j][vr];
        }
    }
}

// ---------------- tanh + sum splits + transpose: part -> wtT[576][6400] ----------------
__global__ __launch_bounds__(256) void tanh_tr_kernel(const float* __restrict__ part,
                                                      const float* __restrict__ bias,
                                                      float* __restrict__ wtT, int nsplit) {
    __shared__ float tile[64][65];
    int oc0 = blockIdx.x * 64, p0 = blockIdx.y * 64;
    int tx = threadIdx.x, ty = threadIdx.y;
#pragma unroll
    for (int k = 0; k < 16; k++) {
        int row = ty + k * 4;
        float s = 0.f;
        for (int sp = 0; sp < nsplit; ++sp)
            s += part[((long)sp * 6400 + oc0 + row) * 576 + p0 + tx];
        tile[row][tx] = tanhf(s + bias[oc0 + row]);
    }
    __syncthreads();
#pragma unroll
    for (int k = 0; k < 16; k++) {
        int rr = ty + k * 4;
        wtT[(long)(p0 + rr) * 6400 + oc0 + tx] = tile[tx][rr];
    }
}

// ---------------- per-pixel stage: fused norm, Wm/XTW/A/B, parallel GJ solve, o, loss ----
__global__ __launch_bounds__(256) void stagec_kernel(const float* __restrict__ design,
                                                     const float* __restrict__ wtT,
                                                     const float* __restrict__ xin,
                                                     const float* __restrict__ gt,
                                                     float* __restrict__ ob,
                                                     float* __restrict__ lp) {
    int p = blockIdx.x;
    int py = p / 24, px = p % 24;
    int tid = threadIdx.x;
    int lane = tid & 63, wv = tid >> 6;
    __shared__ float sX[4800];
    __shared__ float sW[6400];
    __shared__ float sY[1200];
    __shared__ float sP[192];
    __shared__ float sXTW[192];
    __shared__ float sA[144];
    __shared__ float sB[36];
    __shared__ double dM[180];      // augmented [A | B], 12 x 15
    __shared__ float spara[36];
    __shared__ float sred[256];
    __shared__ float sMnW[28], sMxW[28], sMn[7], sMx[7];

    for (int e = tid; e < 4800; e += 256) {
        int n = e / 192, r = e % 192, td = r / 12, cd = r % 12;
        int yy = py + n / 5 - 2, xx = px + n % 5 - 2;
        sX[e] = (yy >= 0 && yy < 24 && xx >= 0 && xx < 24)
                    ? design[(td * 12 + cd) * 576 + yy * 24 + xx] : 0.0f;
    }
    for (int e = tid; e < 6400; e += 256) sW[e] = wtT[(long)p * 6400 + e];
    for (int e = tid; e < 1200; e += 256) {
        int n = e / 48, t = (e % 48) / 3, ch = e % 3;
        int yy = py + n / 5 - 2, xx = px + n % 5 - 2;
        sY[e] = (yy >= 0 && yy < 24 && xx >= 0 && xx < 24)
                    ? xin[(t * 10 + ch) * 576 + yy * 24 + xx] : 0.0f;
    }
    if (tid < 144) sA[tid] = 0.0f;
    if (tid < 36) sB[tid] = 0.0f;
    __syncthreads();

    {
        float mn[7], mx[7];
#pragma unroll
        for (int g = 0; g < 7; g++) { mn[g] = 1e30f; mx[g] = -1e30f; }
        for (int e = tid; e < 4800; e += 256) {
            int cd = e % 12;
            if (cd >= 1) {
                int g = (cd <= 3) ? 0 : (cd == 4) ? 1 : (cd <= 7) ? 2 : 3 + (cd - 8);
                float v = sX[e];
                mn[g] = fminf(mn[g], v);
                mx[g] = fmaxf(mx[g], v);
            }
        }
#pragma unroll
        for (int s2 = 32; s2 >= 1; s2 >>= 1)
#pragma unroll
            for (int g = 0; g < 7; g++) {
                mn[g] = fminf(mn[g], __shfl_xor(mn[g], s2));
                mx[g] = fmaxf(mx[g], __shfl_xor(mx[g], s2));
            }
        if (lane == 0)
#pragma unroll
            for (int g = 0; g < 7; g++) { sMnW[wv * 7 + g] = mn[g]; sMxW[wv * 7 + g] = mx[g]; }
    }
    __syncthreads();
    if (tid < 7) {
        sMn[tid] = fminf(fminf(sMnW[tid], sMnW[7 + tid]), fminf(sMnW[14 + tid], sMnW[21 + tid]));
        sMx[tid] = fmaxf(fmaxf(sMxW[tid], sMxW[7 + tid]), fmaxf(sMxW[14 + tid], sMxW[21 + tid]));
    }
    __syncthreads();
    for (int e = tid; e < 4800; e += 256) {
        int cd = e % 12;
        if (cd >= 1) {
            int g = (cd <= 3) ? 0 : (cd == 4) ? 1 : (cd <= 7) ? 2 : 3 + (cd - 8);
            sX[e] = (sX[e] - sMn[g]) / (sMx[g] - sMn[g] + 0.001f);
        }
    }
    __syncthreads();

    for (int n = 0; n < 25; n++) {
        const float* X = sX + n * 192;
        const float* W = sW + n * 256;
        if (tid < 192) {
            int c = tid >> 4, j = tid & 15;
            float s = 0.0f;
#pragma unroll
            for (int t = 0; t < 16; t++) s = fmaf(X[t * 12 + c], W[t * 16 + j], s);
            sP[tid] = s;
        }
        __syncthreads();
        if (tid < 192) {
            int c = tid >> 4, u = tid & 15;
            float s = X[u * 12 + c];
#pragma unroll
            for (int j = 0; j < 16; j++) s = fmaf(sP[c * 16 + j], W[u * 16 + j], s);
            sXTW[tid] = s;
        }
        __syncthreads();
        if (tid < 144) {
            int c = tid / 12, d2 = tid % 12;
            float s = 0.0f;
#pragma unroll
            for (int t = 0; t < 16; t++) s = fmaf(sXTW[c * 16 + t], X[t * 12 + d2], s);
            sA[tid] += s;
        } else if (tid < 180) {
            int e = tid - 144;
            int c = e / 3, ch = e % 3;
            float s = 0.0f;
#pragma unroll
            for (int t = 0; t < 16; t++) s = fmaf(sXTW[c * 16 + t], sY[n * 48 + t * 3 + ch], s);
            sB[e] += s;
        }
        __syncthreads();
    }

    if (tid < 144) dM[(tid / 12) * 15 + (tid % 12)] = (double)sA[tid] + ((tid % 13 == 0) ? 0.01 : 0.0);
    if (tid < 36) dM[(tid / 3) * 15 + 12 + (tid % 3)] = (double)sB[tid];
    __syncthreads();
    {
        int rr = (tid < 180) ? tid / 15 : 11;
        int c2 = (tid < 180) ? tid % 15 : 14;
#pragma unroll 1
        for (int k = 0; k < 12; ++k) {
            double pinv = 1.0 / dM[k * 15 + k];
            double fkc = dM[k * 15 + c2] * pinv;
            double frk = dM[rr * 15 + k];
            double cur = dM[rr * 15 + c2];
            __syncthreads();
            if (tid < 180) dM[rr * 15 + c2] = (rr == k) ? fkc : fma(-frk, fkc, cur);
            __syncthreads();
        }
    }
    if (tid < 36) spara[tid] = (float)dM[(tid / 3) * 15 + 12 + (tid % 3)];
    __syncthreads();

    float lsum = 0.0f;
    for (int e = tid; e < 1200; e += 256) {
        int n = e / 48, td = (e % 48) / 3, ch = e % 3;
        float s = 0.0f;
#pragma unroll
        for (int c = 0; c < 12; c++) s = fmaf(sX[n * 192 + td * 12 + c], spara[c * 3 + ch], s);
        ob[((long)(p * 25 + n)) * 48 + td * 3 + ch] = s;
        int yy = py + n / 5 - 2, xx = px + n % 5 - 2;
        float rv = (yy >= 0 && yy < 24 && xx >= 0 && xx < 24)
                       ? gt[(td * 3 + ch) * 576 + yy * 24 + xx] : 0.0f;
        lsum += fabsf(s - rv);
    }
    sred[tid] = lsum;
    __syncthreads();
    for (int s = 128; s >= 1; s >>= 1) {
        if (tid < s) sred[tid] += sred[tid + s];
        __syncthreads();
    }
    if (tid == 0) lp[p] = sred[0];
}

// ---------------- fold (overlap-add) + normalize ----------------
__global__ void fold_kernel(const float* __restrict__ ob, float* __restrict__ out) {
    int idx = blockIdx.x * 256 + threadIdx.x;
    if (idx >= 27648) return;
    int td = idx / 1728;
    int rem = idx % 1728;
    int ch = rem / 576;
    int p = rem % 576;
    int y = p / 24, x = p % 24;
    float num = 0.0f;
    int den = 0;
    for (int i = 0; i < 5; i++) {
        int yy = y + 2 - i;
        if (yy < 0 || yy >= 24) continue;
        for (int j = 0; j < 5; j++) {
            int xx = x + 2 - j;
            if (xx < 0 || xx >= 24) continue;
            num += ob[((long)((yy * 24 + xx) * 25 + i * 5 + j)) * 48 + td * 3 + ch];
            den++;
        }
    }
    out[idx] = num / (float)den;
}

// ---------------- final loss reduce ----------------
__global__ __launch_bounds__(64) void loss_kernel(const float* __restrict__ lp,
                                                  float* __restrict__ out) {
    int t = threadIdx.x;
    float s = 0.0f;
    for (int e = t; e < 576; e += 64) s += lp[e];
#pragma unroll
    for (int d = 32; d >= 1; d >>= 1) s += __shfl_xor(s, d);
    if (t == 0) out[27648] = s / 691200.0f;
}

// ---------------- launch ----------------
extern "C" void kernel_launch(void* const* d_in, const int* in_sizes, int n_in,
                              void* d_out, int out_size, void* d_ws, size_t ws_size,
                              hipStream_t stream) {
    const float* x      = (const float*)d_in[0];
    const float* design = (const float*)d_in[1];
    const float* gt     = (const float*)d_in[2];
    const float* w1     = (const float*)d_in[3];
    const float* b1     = (const float*)d_in[4];
    const float* w2     = (const float*)d_in[5];
    const float* b2     = (const float*)d_in[6];
    const float* w3     = (const float*)d_in[7];
    const float* b3     = (const float*)d_in[8];
    const float* wf     = (const float*)d_in[9];
    const float* bf     = (const float*)d_in[10];
    float* out = (float*)d_out;
    char* wsb  = (char*)d_ws;

    float* part = (float*)(wsb + OFF_PART);
    char*  x2t  = wsb + OFF_X2T;
    float* wtT  = (float*)(wsb + OFF_WTT);   // overlaps X2T (dead by then)
    float* act  = (float*)(wsb + OFF_ACT);
    float* ob   = (float*)(wsb + OFF_OB);
    float* lp   = (float*)(wsb + OFF_LP);

    // conv1: K=1440 (45 chunks), ksplit=15 x cps=3 -> 480 blocks
    im2col_kernel<<<102, 256, 0, stream>>>(x, x2t, 45 * 576);
    conv_mfma9_kernel<0><<<dim3(8, 4, 15), 256, 0, stream>>>(x2t, w1, part, 1440, 3, 1024);
    finalize_kernel<<<2304, 256, 0, stream>>>(part, b1, act, 589824, 15);
    // conv2: K=9216 (288 chunks), ksplit=16 x cps=18 -> 512 blocks (2/CU, 1 round)
    im2col_kernel<<<648, 256, 0, stream>>>(act, x2t, 288 * 576);
    conv_mfma9_kernel<0><<<dim3(8, 4, 16), 256, 0, stream>>>(x2t, w2, part, 9216, 18, 1024);
    finalize_kernel<<<2304, 256, 0, stream>>>(part, b2, act, 589824, 16);
    // conv3
    im2col_kernel<<<648, 256, 0, stream>>>(act, x2t, 288 * 576);
    conv_mfma9_kernel<0><<<dim3(8, 4, 16), 256, 0, stream>>>(x2t, w3, part, 9216, 18, 1024);
    finalize_kernel<<<2304, 256, 0, stream>>>(part, b3, act, 589824, 16);
    // convf: cout=6400, ksplit=2 x cps=144 -> 400 blocks, XCD-bijective swizzle
    im2col_kernel<<<648, 256, 0, stream>>>(act, x2t, 288 * 576);
    conv_mfma9_kernel<1><<<400, 256, 0, stream>>>(x2t, wf, part, 9216, 144, 6400);
    tanh_tr_kernel<<<dim3(100, 9), dim3(64, 4), 0, stream>>>(part, bf, wtT, 2);

    stagec_kernel<<<576, 256, 0, stream>>>(design, wtT, x, gt, ob, lp);
    fold_kernel<<<108, 256, 0, stream>>>(ob, out);
    loss_kernel<<<1, 64, 0, stream>>>(lp, out);
}

// Round 11
// 467.842 us; speedup vs baseline: 1.5634x; 1.5634x over previous
//
#include <hip/hip_runtime.h>
#include <math.h>

// ---------------- problem constants ----------------
// b=1, t=16, ch_in=10, h=w=24, t_de=16, ch_de=12, K=5, N=25
// hw=576, M = 14400; out: 27648 + loss = 27649 floats

typedef __attribute__((ext_vector_type(8))) short sh8;
typedef __attribute__((ext_vector_type(4))) float f32x4;

// ---------------- workspace layout (byte offsets) ----------------
#define OFF_PART 0UL              // 58,982,400 (convf: 4 splits x 6400x576x4)
#define OFF_X2T  58982400UL       // 21,233,664 (288 chunks x 73728)
#define OFF_WTT  58982400UL       // overlaps X2T (X2T dead when WTT written)
#define OFF_ACT  80216064UL       // 2,359,296
#define OFF_OB   82575360UL       // 2,764,800
#define OFF_LP   85340160UL       // 2,304
// total ~85.3 MB (known-safe, r9 layout)

// X2T layout: [kc][pg(36)][plane(2: hi,lo)][q(4)][px16(16)][16B]
//   chunk stride 36*2048 = 73728 B; pg block 2048 B; plane 1024 B.

// ---------------- helpers ----------------
__device__ inline void glds16(const void* gsrc, void* ldst) {
    __builtin_amdgcn_global_load_lds((const __attribute__((address_space(1))) void*)gsrc,
                                     (__attribute__((address_space(3))) void*)ldst, 16, 0, 0);
}

// ---------------- im2col: act fp32 [C][24][24] -> X2T (frag-coalesced layout) ----------------
__global__ __launch_bounds__(256) void im2col_kernel(const float* __restrict__ act,
                                                     char* __restrict__ x2t, int nrows) {
    int row = blockIdx.x * 256 + threadIdx.x;
    if (row >= nrows) return;
    int kc = row / 576, px = row % 576;
    int y = px / 24, x = px % 24;
    int k0 = kc * 32;
    int ic = k0 / 9;
    int tap = k0 - ic * 9;
    sh8 hv[4], lv[4];
#pragma unroll
    for (int e = 0; e < 32; ++e) {
        int dy = tap / 3, dx = tap - dy * 3;
        int yy = y + dy - 1, xx = x + dx - 1;
        float v = (yy >= 0 && yy < 24 && xx >= 0 && xx < 24)
                      ? act[ic * 576 + yy * 24 + xx] : 0.0f;
        unsigned u = __builtin_bit_cast(unsigned, v);
        hv[e / 8][e % 8] = (short)(u >> 16);
        float fh = __builtin_bit_cast(float, u & 0xFFFF0000u);
        lv[e / 8][e % 8] = (short)(__builtin_bit_cast(unsigned, v - fh) >> 16);
        if (++tap == 9) { tap = 0; ++ic; }
    }
    int pg = px >> 4, l15 = px & 15;
    char* dst = x2t + (long)kc * 73728 + pg * 2048 + l15 * 16;
#pragma unroll
    for (int q = 0; q < 4; ++q) {
        *(sh8*)(dst + q * 256) = hv[q];
        *(sh8*)(dst + 1024 + q * 256) = lv[q];
    }
}

// ---------------- sum K-splits + bias + leaky -> act fp32 ----------------
__global__ void finalize_kernel(const float* __restrict__ part,
                                const float* __restrict__ bias,
                                float* __restrict__ act, int total, int nsplit) {
    int idx = blockIdx.x * 256 + threadIdx.x;
    if (idx >= total) return;
    float s = 0.0f;
    for (int k = 0; k < nsplit; k++) s += part[(long)k * total + idx];
    s += bias[idx / 576];
    act[idx] = s >= 0.0f ? s : 0.01f * s;
}

// ---------------- conv kernel A (r9-proven): 128oc x 144px, 4 oc-split waves, 4 bl/CU ----
__global__ __launch_bounds__(256, 4)
void conv_mfma8_kernel(const char* __restrict__ x2t,
                       const float* __restrict__ wgt,   // [cout][K] fp32, K = cin*9
                       float* __restrict__ part,        // [ksplit][cout][576]
                       int K, int cps, int cout) {
    __shared__ __align__(1024) char sB[18432];   // [j(9)][plane(2)][1024B]
    __shared__ __align__(1024) char sA[16384];   // hi[128][64B] @0, lo @8192

    const int tid = threadIdx.x;
    const int lane = tid & 63;
    const int w = tid >> 6;
    const int q = lane >> 4, ln15 = lane & 15;
    const int lane16 = lane * 16;

    const int ocb = blockIdx.x, pxq = blockIdx.y, s = blockIdx.z;
    const int c0 = s * cps;

    const int st_oc = tid >> 1, st_h = tid & 1;
    const float* wrow = wgt + (long)(ocb * 128 + st_oc) * K + st_h * 16;
    const int wslot0 = (((st_h * 2 + 0) + (st_oc >> 1)) & 3) << 4;
    const int wslot1 = (((st_h * 2 + 1) + (st_oc >> 1)) & 3) << 4;

    int aoff[2];
#pragma unroll
    for (int ot = 0; ot < 2; ++ot) {
        int oc = w * 32 + ot * 16 + ln15;
        aoff[ot] = oc * 64 + (((q + (oc >> 1)) & 3) << 4);
    }

    f32x4 acc[2][9];
#pragma unroll
    for (int a = 0; a < 2; ++a)
#pragma unroll
        for (int j = 0; j < 9; ++j) acc[a][j] = f32x4{0.f, 0.f, 0.f, 0.f};

#pragma unroll 1
    for (int t = 0; t < cps; ++t) {
        const int cc = c0 + t;
        __syncthreads();
        const char* bsrc = x2t + (long)cc * 73728 + pxq * 18432;
        for (int u = w; u < 18; u += 4)
            glds16(bsrc + u * 1024 + lane16, sB + u * 1024);
        {
            const float* p = wrow + (long)cc * 32;
            float4 a0 = *(const float4*)(p);
            float4 a1 = *(const float4*)(p + 4);
            float4 a2 = *(const float4*)(p + 8);
            float4 a3 = *(const float4*)(p + 12);
            float av[16] = {a0.x, a0.y, a0.z, a0.w, a1.x, a1.y, a1.z, a1.w,
                            a2.x, a2.y, a2.z, a2.w, a3.x, a3.y, a3.z, a3.w};
            sh8 h8[2], l8[2];
#pragma unroll
            for (int e = 0; e < 16; ++e) {
                unsigned u = __builtin_bit_cast(unsigned, av[e]);
                h8[e / 8][e % 8] = (short)(u >> 16);
                float fh = __builtin_bit_cast(float, u & 0xFFFF0000u);
                l8[e / 8][e % 8] = (short)(__builtin_bit_cast(unsigned, av[e] - fh) >> 16);
            }
            char* hb = sA + st_oc * 64;
            *(sh8*)(hb + wslot0) = h8[0];
            *(sh8*)(hb + wslot1) = h8[1];
            *(sh8*)(hb + 8192 + wslot0) = l8[0];
            *(sh8*)(hb + 8192 + wslot1) = l8[1];
        }
        asm volatile("s_waitcnt vmcnt(0)" ::: "memory");
        __syncthreads();

        sh8 ah[2], al[2];
#pragma unroll
        for (int ot = 0; ot < 2; ++ot) {
            ah[ot] = *(const sh8*)(sA + aoff[ot]);
            al[ot] = *(const sh8*)(sA + 8192 + aoff[ot]);
        }
#pragma unroll
        for (int j = 0; j < 9; ++j) {
            sh8 bh = *(const sh8*)(sB + j * 2048 + lane16);
            sh8 bl = *(const sh8*)(sB + j * 2048 + 1024 + lane16);
#pragma unroll
            for (int ot = 0; ot < 2; ++ot) {
                acc[ot][j] = __builtin_amdgcn_mfma_f32_16x16x32_bf16(ah[ot], bh, acc[ot][j], 0, 0, 0);
                acc[ot][j] = __builtin_amdgcn_mfma_f32_16x16x32_bf16(al[ot], bh, acc[ot][j], 0, 0, 0);
                acc[ot][j] = __builtin_amdgcn_mfma_f32_16x16x32_bf16(ah[ot], bl, acc[ot][j], 0, 0, 0);
            }
        }
    }
#pragma unroll
    for (int ot = 0; ot < 2; ++ot) {
        int oc0 = ocb * 128 + w * 32 + ot * 16 + q * 4;
#pragma unroll
        for (int j = 0; j < 9; ++j) {
            int px = pxq * 144 + j * 16 + ln15;
#pragma unroll
            for (int vr = 0; vr < 4; ++vr)
                part[((long)s * cout + oc0 + vr) * 576 + px] = acc[ot][j][vr];
        }
    }
}

// ---------------- conv kernel F (r4-proven structure): 128oc x 288px, wo2 x wp2 waves ----
// A: fp32 staged DIRECT global->LDS via glds with pre-swizzled source (no reg round-trip);
// B: glds 36KB; ONE vmcnt(0) per chunk; per-wave fp32->bf16 hi/lo convert; 52.9KB LDS.
__global__ __launch_bounds__(256, 2)
void conv_mfmaF_kernel(const char* __restrict__ x2t,
                       const float* __restrict__ wgt,   // [cout][K] fp32
                       float* __restrict__ part,        // [ksplit][cout][576]
                       int K, int cps, int cout) {
    __shared__ __align__(1024) char sA[16384];   // fp32, 128 rows x 128B, XOR-swizzled
    __shared__ __align__(1024) char sB[36864];   // [pg_local(18)][plane(2)][1024B]

    const int tid = threadIdx.x;
    const int lane = tid & 63;
    const int w = tid >> 6;
    const int wo = w >> 1, wp = w & 1;
    const int q = lane >> 4, ln15 = lane & 15;
    const int lane16 = lane * 16;

    // bijective XCD swizzle: 400 = 8 x 50; weight-slice sharers (pxh pair) adjacent
    int g = blockIdx.x;
    int p = (g & 7) * 50 + (g >> 3);
    const int pxh = p & 1;
    const int s = (p >> 1) & 3;
    const int ocb = p >> 3;
    const long K4 = (long)K * 4;
    const int c0 = s * cps;

    const int arow = lane >> 3;          // 0..7 within 8-row granule
    const int acol = (lane & 7) * 16;    // byte within 128-B row
    const int sw = (ln15 & 7) << 4;      // read-side XOR

    f32x4 acc[4][9];
#pragma unroll
    for (int a = 0; a < 4; ++a)
#pragma unroll
        for (int j = 0; j < 9; ++j) acc[a][j] = f32x4{0.f, 0.f, 0.f, 0.f};

    const char* wsrc0 = (const char*)wgt + (long)(ocb * 128) * K4;

#pragma unroll 1
    for (int t = 0; t < cps; ++t) {
        const int cc = c0 + t;
        __syncthreads();
        {
            // A: 128 rows x 128 B fp32; source byte pre-swizzled so LDS phys is XOR-laid
            const char* wsrc = wsrc0 + (long)cc * 128;
            for (int it = w; it < 16; it += 4) {
                int r = it * 8 + arow;
                glds16(wsrc + (long)r * K4 + (acol ^ ((r & 7) << 4)), sA + it * 1024);
            }
            // B: 36 KB (18 pg x 2 planes), frag-coalesced
            const char* bsrc = x2t + (long)cc * 73728 + pxh * 36864;
            for (int u = w; u < 36; u += 4)
                glds16(bsrc + u * 1024 + lane16, sB + u * 1024);
        }
        asm volatile("s_waitcnt vmcnt(0)" ::: "memory");
        __syncthreads();

        // A fragments: read swizzled fp32, convert to bf16 hi/lo in-register
        sh8 ah[4], al[4];
#pragma unroll
        for (int ot = 0; ot < 4; ++ot) {
            const char* ap = sA + (wo * 64 + ot * 16 + ln15) * 128;
            float4 a0 = *(const float4*)(ap + ((q * 32) ^ sw));
            float4 a1 = *(const float4*)(ap + ((q * 32 + 16) ^ sw));
            float av[8] = {a0.x, a0.y, a0.z, a0.w, a1.x, a1.y, a1.z, a1.w};
#pragma unroll
            for (int e = 0; e < 8; ++e) {
                unsigned u = __builtin_bit_cast(unsigned, av[e]);
                ah[ot][e] = (short)(u >> 16);
                float fh = __builtin_bit_cast(float, u & 0xFFFF0000u);
                al[ot][e] = (short)(__builtin_bit_cast(unsigned, av[e] - fh) >> 16);
            }
        }
        // B fragments + MFMA
#pragma unroll
        for (int j = 0; j < 9; ++j) {
            const char* bp = sB + (wp * 9 + j) * 2048 + lane16;
            sh8 bh = *(const sh8*)(bp);
            sh8 bl = *(const sh8*)(bp + 1024);
#pragma unroll
            for (int ot = 0; ot < 4; ++ot) {
                acc[ot][j] = __builtin_amdgcn_mfma_f32_16x16x32_bf16(ah[ot], bh, acc[ot][j], 0, 0, 0);
                acc[ot][j] = __builtin_amdgcn_mfma_f32_16x16x32_bf16(al[ot], bh, acc[ot][j], 0, 0, 0);
                acc[ot][j] = __builtin_amdgcn_mfma_f32_16x16x32_bf16(ah[ot], bl, acc[ot][j], 0, 0, 0);
            }
        }
    }
    // epilogue
#pragma unroll
    for (int ot = 0; ot < 4; ++ot) {
        int oc0 = ocb * 128 + wo * 64 + ot * 16 + q * 4;
#pragma unroll
        for (int j = 0; j < 9; ++j) {
            int px = pxh * 288 + wp * 144 + j * 16 + ln15;
#pragma unroll
            for (int vr = 0; vr < 4; ++vr)
                part[((long)s * cout + oc0 + vr) * 576 + px] = acc[ot][j][vr];
        }
    }
}

// ---------------- tanh + sum splits + transpose: part -> wtT[576][6400] ----------------
__global__ __launch_bounds__(256) void tanh_tr_kernel(const float* __restrict__ part,
                                                      const float* __restrict__ bias,
                                                      float* __restrict__ wtT, int nsplit) {
    __shared__ float tile[64][65];
    int oc0 = blockIdx.x * 64, p0 = blockIdx.y * 64;
    int tx = threadIdx.x, ty = threadIdx.y;
#pragma unroll
    for (int k = 0; k < 16; k++) {
        int row = ty + k * 4;
        float s = 0.f;
        for (int sp = 0; sp < nsplit; ++sp)
            s += part[((long)sp * 6400 + oc0 + row) * 576 + p0 + tx];
        tile[row][tx] = tanhf(s + bias[oc0 + row]);
    }
    __syncthreads();
#pragma unroll
    for (int k = 0; k < 16; k++) {
        int rr = ty + k * 4;
        wtT[(long)(p0 + rr) * 6400 + oc0 + tx] = tile[tx][rr];
    }
}

// ---------------- per-pixel stage: fused norm, Wm/XTW/A/B, parallel GJ solve, o, loss ----
__global__ __launch_bounds__(256) void stagec_kernel(const float* __restrict__ design,
                                                     const float* __restrict__ wtT,
                                                     const float* __restrict__ xin,
                                                     const float* __restrict__ gt,
                                                     float* __restrict__ ob,
                                                     float* __restrict__ lp) {
    int p = blockIdx.x;
    int py = p / 24, px = p % 24;
    int tid = threadIdx.x;
    int lane = tid & 63, wv = tid >> 6;
    __shared__ float sX[4800];
    __shared__ float sW[6400];
    __shared__ float sY[1200];
    __shared__ float sP[192];
    __shared__ float sXTW[192];
    __shared__ float sA[144];
    __shared__ float sB[36];
    __shared__ double dM[180];
    __shared__ float spara[36];
    __shared__ float sred[256];
    __shared__ float sMnW[28], sMxW[28], sMn[7], sMx[7];

    for (int e = tid; e < 4800; e += 256) {
        int n = e / 192, r = e % 192, td = r / 12, cd = r % 12;
        int yy = py + n / 5 - 2, xx = px + n % 5 - 2;
        sX[e] = (yy >= 0 && yy < 24 && xx >= 0 && xx < 24)
                    ? design[(td * 12 + cd) * 576 + yy * 24 + xx] : 0.0f;
    }
    for (int e = tid; e < 6400; e += 256) sW[e] = wtT[(long)p * 6400 + e];
    for (int e = tid; e < 1200; e += 256) {
        int n = e / 48, t = (e % 48) / 3, ch = e % 3;
        int yy = py + n / 5 - 2, xx = px + n % 5 - 2;
        sY[e] = (yy >= 0 && yy < 24 && xx >= 0 && xx < 24)
                    ? xin[(t * 10 + ch) * 576 + yy * 24 + xx] : 0.0f;
    }
    if (tid < 144) sA[tid] = 0.0f;
    if (tid < 36) sB[tid] = 0.0f;
    __syncthreads();

    {
        float mn[7], mx[7];
#pragma unroll
        for (int g = 0; g < 7; g++) { mn[g] = 1e30f; mx[g] = -1e30f; }
        for (int e = tid; e < 4800; e += 256) {
            int cd = e % 12;
            if (cd >= 1) {
                int g = (cd <= 3) ? 0 : (cd == 4) ? 1 : (cd <= 7) ? 2 : 3 + (cd - 8);
                float v = sX[e];
                mn[g] = fminf(mn[g], v);
                mx[g] = fmaxf(mx[g], v);
            }
        }
#pragma unroll
        for (int s2 = 32; s2 >= 1; s2 >>= 1)
#pragma unroll
            for (int g = 0; g < 7; g++) {
                mn[g] = fminf(mn[g], __shfl_xor(mn[g], s2));
                mx[g] = fmaxf(mx[g], __shfl_xor(mx[g], s2));
            }
        if (lane == 0)
#pragma unroll
            for (int g = 0; g < 7; g++) { sMnW[wv * 7 + g] = mn[g]; sMxW[wv * 7 + g] = mx[g]; }
    }
    __syncthreads();
    if (tid < 7) {
        sMn[tid] = fminf(fminf(sMnW[tid], sMnW[7 + tid]), fminf(sMnW[14 + tid], sMnW[21 + tid]));
        sMx[tid] = fmaxf(fmaxf(sMxW[tid], sMxW[7 + tid]), fmaxf(sMxW[14 + tid], sMxW[21 + tid]));
    }
    __syncthreads();
    for (int e = tid; e < 4800; e += 256) {
        int cd = e % 12;
        if (cd >= 1) {
            int g = (cd <= 3) ? 0 : (cd == 4) ? 1 : (cd <= 7) ? 2 : 3 + (cd - 8);
            sX[e] = (sX[e] - sMn[g]) / (sMx[g] - sMn[g] + 0.001f);
        }
    }
    __syncthreads();

    for (int n = 0; n < 25; n++) {
        const float* X = sX + n * 192;
        const float* W = sW + n * 256;
        if (tid < 192) {
            int c = tid >> 4, j = tid & 15;
            float s = 0.0f;
#pragma unroll
            for (int t = 0; t < 16; t++) s = fmaf(X[t * 12 + c], W[t * 16 + j], s);
            sP[tid] = s;
        }
        __syncthreads();
        if (tid < 192) {
            int c = tid >> 4, u = tid & 15;
            float s = X[u * 12 + c];
#pragma unroll
            for (int j = 0; j < 16; j++) s = fmaf(sP[c * 16 + j], W[u * 16 + j], s);
            sXTW[tid] = s;
        }
        __syncthreads();
        if (tid < 144) {
            int c = tid / 12, d2 = tid % 12;
            float s = 0.0f;
#pragma unroll
            for (int t = 0; t < 16; t++) s = fmaf(sXTW[c * 16 + t], X[t * 12 + d2], s);
            sA[tid] += s;
        } else if (tid < 180) {
            int e = tid - 144;
            int c = e / 3, ch = e % 3;
            float s = 0.0f;
#pragma unroll
            for (int t = 0; t < 16; t++) s = fmaf(sXTW[c * 16 + t], sY[n * 48 + t * 3 + ch], s);
            sB[e] += s;
        }
        __syncthreads();
    }

    if (tid < 144) dM[(tid / 12) * 15 + (tid % 12)] = (double)sA[tid] + ((tid % 13 == 0) ? 0.01 : 0.0);
    if (tid < 36) dM[(tid / 3) * 15 + 12 + (tid % 3)] = (double)sB[tid];
    __syncthreads();
    {
        int rr = (tid < 180) ? tid / 15 : 11;
        int c2 = (tid < 180) ? tid % 15 : 14;
#pragma unroll 1
        for (int k = 0; k < 12; ++k) {
            double pinv = 1.0 / dM[k * 15 + k];
            double fkc = dM[k * 15 + c2] * pinv;
            double frk = dM[rr * 15 + k];
            double cur = dM[rr * 15 + c2];
            __syncthreads();
            if (tid < 180) dM[rr * 15 + c2] = (rr == k) ? fkc : fma(-frk, fkc, cur);
            __syncthreads();
        }
    }
    if (tid < 36) spara[tid] = (float)dM[(tid / 3) * 15 + 12 + (tid % 3)];
    __syncthreads();

    float lsum = 0.0f;
    for (int e = tid; e < 1200; e += 256) {
        int n = e / 48, td = (e % 48) / 3, ch = e % 3;
        float s = 0.0f;
#pragma unroll
        for (int c = 0; c < 12; c++) s = fmaf(sX[n * 192 + td * 12 + c], spara[c * 3 + ch], s);
        ob[((long)(p * 25 + n)) * 48 + td * 3 + ch] = s;
        int yy = py + n / 5 - 2, xx = px + n % 5 - 2;
        float rv = (yy >= 0 && yy < 24 && xx >= 0 && xx < 24)
                       ? gt[(td * 3 + ch) * 576 + yy * 24 + xx] : 0.0f;
        lsum += fabsf(s - rv);
    }
    sred[tid] = lsum;
    __syncthreads();
    for (int s = 128; s >= 1; s >>= 1) {
        if (tid < s) sred[tid] += sred[tid + s];
        __syncthreads();
    }
    if (tid == 0) lp[p] = sred[0];
}

// ---------------- fold (overlap-add) + normalize ----------------
__global__ void fold_kernel(const float* __restrict__ ob, float* __restrict__ out) {
    int idx = blockIdx.x * 256 + threadIdx.x;
    if (idx >= 27648) return;
    int td = idx / 1728;
    int rem = idx % 1728;
    int ch = rem / 576;
    int p = rem % 576;
    int y = p / 24, x = p % 24;
    float num = 0.0f;
    int den = 0;
    for (int i = 0; i < 5; i++) {
        int yy = y + 2 - i;
        if (yy < 0 || yy >= 24) continue;
        for (int j = 0; j < 5; j++) {
            int xx = x + 2 - j;
            if (xx < 0 || xx >= 24) continue;
            num += ob[((long)((yy * 24 + xx) * 25 + i * 5 + j)) * 48 + td * 3 + ch];
            den++;
        }
    }
    out[idx] = num / (float)den;
}

// ---------------- final loss reduce ----------------
__global__ __launch_bounds__(64) void loss_kernel(const float* __restrict__ lp,
                                                  float* __restrict__ out) {
    int t = threadIdx.x;
    float s = 0.0f;
    for (int e = t; e < 576; e += 64) s += lp[e];
#pragma unroll
    for (int d = 32; d >= 1; d >>= 1) s += __shfl_xor(s, d);
    if (t == 0) out[27648] = s / 691200.0f;
}

// ---------------- launch ----------------
extern "C" void kernel_launch(void* const* d_in, const int* in_sizes, int n_in,
                              void* d_out, int out_size, void* d_ws, size_t ws_size,
                              hipStream_t stream) {
    const float* x      = (const float*)d_in[0];
    const float* design = (const float*)d_in[1];
    const float* gt     = (const float*)d_in[2];
    const float* w1     = (const float*)d_in[3];
    const float* b1     = (const float*)d_in[4];
    const float* w2     = (const float*)d_in[5];
    const float* b2     = (const float*)d_in[6];
    const float* w3     = (const float*)d_in[7];
    const float* b3     = (const float*)d_in[8];
    const float* wf     = (const float*)d_in[9];
    const float* bf     = (const float*)d_in[10];
    float* out = (float*)d_out;
    char* wsb  = (char*)d_ws;

    float* part = (float*)(wsb + OFF_PART);
    char*  x2t  = wsb + OFF_X2T;
    float* wtT  = (float*)(wsb + OFF_WTT);   // overlaps X2T (dead by then)
    float* act  = (float*)(wsb + OFF_ACT);
    float* ob   = (float*)(wsb + OFF_OB);
    float* lp   = (float*)(wsb + OFF_LP);

    // conv1: K=1440 (45 chunks), ksplit=15 x cps=3 -> 480 blocks
    im2col_kernel<<<102, 256, 0, stream>>>(x, x2t, 45 * 576);
    conv_mfma8_kernel<<<dim3(8, 4, 15), 256, 0, stream>>>(x2t, w1, part, 1440, 3, 1024);
    finalize_kernel<<<2304, 256, 0, stream>>>(part, b1, act, 589824, 15);
    // conv2: K=9216 (288 chunks), ksplit=16 x cps=18 -> 512 blocks
    im2col_kernel<<<648, 256, 0, stream>>>(act, x2t, 288 * 576);
    conv_mfma8_kernel<<<dim3(8, 4, 16), 256, 0, stream>>>(x2t, w2, part, 9216, 18, 1024);
    finalize_kernel<<<2304, 256, 0, stream>>>(part, b2, act, 589824, 16);
    // conv3
    im2col_kernel<<<648, 256, 0, stream>>>(act, x2t, 288 * 576);
    conv_mfma8_kernel<<<dim3(8, 4, 16), 256, 0, stream>>>(x2t, w3, part, 9216, 18, 1024);
    finalize_kernel<<<2304, 256, 0, stream>>>(part, b3, act, 589824, 16);
    // convf: cout=6400, ksplit=4 x cps=72 -> 400 blocks (all-resident at 2/CU), swizzled
    im2col_kernel<<<648, 256, 0, stream>>>(act, x2t, 288 * 576);
    conv_mfmaF_kernel<<<400, 256, 0, stream>>>(x2t, wf, part, 9216, 72, 6400);
    tanh_tr_kernel<<<dim3(100, 9), dim3(64, 4), 0, stream>>>(part, bf, wtT, 4);

    stagec_kernel<<<576, 256, 0, stream>>>(design, wtT, x, gt, ob, lp);
    fold_kernel<<<108, 256, 0, stream>>>(ob, out);
    loss_kernel<<<1, 64, 0, stream>>>(lp, out);
}